// Round 3
// baseline (587.886 us; speedup 1.0000x reference)
//
#include <hip/hip_runtime.h>

#define GO_H  19
#define GO_HP 21             // padded dim (halo of 1)
#define NCELL 361            // 19*19
#define NPAD  441            // 21*21
#define G     2              // boards per block
#define NC_G  (G * NCELL)    // 722

__global__ __launch_bounds__(256) void go_features_kernel(
    const float* __restrict__ stones,      // (B, 2, 19, 19)
    const int*   __restrict__ cur_player,  // (B,)
    const int*   __restrict__ ko,          // (B, 2)
    float*       __restrict__ out)         // (B, 5, 19, 19)
{
    __shared__ float cur_p[G][NPAD];
    __shared__ float opp_p[G][NPAD];
    __shared__ float emp_p[G][NPAD];
    __shared__ float weak_p[G][NPAD];
    __shared__ unsigned short lut[NCELL];  // c -> padded index
    __shared__ int cp_s[G], koc_s[G];

    const int tid = threadIdx.x;
    const int gb  = blockIdx.x * G;

    // ---- Region A (no internal barrier: halo stores, LUT stores, interior
    // stores hit disjoint LDS addresses; nothing here reads LDS). ----

    // A1: zero halos of all planes + build c->pi LUT.
    #pragma unroll
    for (int k = 0; k < 2; ++k) {
        int i = tid + k * 256;
        if (i < NPAD) {
            int r = i / GO_HP, col = i - r * GO_HP;
            if (r == 0 || r == GO_HP - 1 || col == 0 || col == GO_HP - 1) {
                #pragma unroll
                for (int g = 0; g < G; ++g) {
                    cur_p[g][i] = 0.f; opp_p[g][i] = 0.f;
                    emp_p[g][i] = 0.f; weak_p[g][i] = 0.f;
                }
            } else {
                lut[(r - 1) * GO_H + (col - 1)] = (unsigned short)i;
            }
        }
    }

    // A2: per-board scalars (read again from LDS only after the barrier).
    if (tid < G) {
        int b = gb + tid;
        cp_s[tid] = cur_player[b];
        int kr = ko[2 * b], kc = ko[2 * b + 1];
        int rr = min(max(kr, 0), GO_H - 1);
        int cc = min(max(kc, 0), GO_H - 1);
        koc_s[tid] = (kr >= 0) ? rr * GO_H + cc : -1;
    }

    // A3: interior fill of cur/opp/emp (pi computed arithmetically; LUT not
    // readable yet). cp read straight from global (L1 broadcast).
    {
        int c = tid, g = 0;
        #pragma unroll
        for (int k = 0; k < 3; ++k) {
            if (g < G) {
                int   cp = cur_player[gb + g];
                const float* bp = stones + (size_t)(gb + g) * (2 * NCELL);
                float s0 = bp[c];
                float s1 = bp[NCELL + c];
                int r = c / GO_H, col = c - r * GO_H;
                int pi = (r + 1) * GO_HP + col + 1;
                cur_p[g][pi] = cp ? s1 : s0;
                opp_p[g][pi] = cp ? s0 : s1;
                emp_p[g][pi] = 1.f - s0 - s1;
            }
            c += 256; if (c >= NCELL) { c -= NCELL; ++g; }
        }
    }
    __syncthreads();

    // ---- P2: weak = (opp > 0.5) && (nbr(opp) == 1), interior only
    // (weak halo already zeroed). Constant neighbor offsets -> ds_read2. ----
    {
        int c = tid, g = 0;
        #pragma unroll
        for (int k = 0; k < 3; ++k) {
            if (g < G) {
                int pi = lut[c];
                float o = opp_p[g][pi];
                float s = opp_p[g][pi - GO_HP] + opp_p[g][pi + GO_HP]
                        + opp_p[g][pi - 1]     + opp_p[g][pi + 1];
                weak_p[g][pi] = (o > 0.5f && s == 1.0f) ? 1.f : 0.f;
            }
            c += 256; if (c >= NCELL) { c -= NCELL; ++g; }
        }
    }
    __syncthreads();

    // ---- P3: legal, cur_lib, all 5 planes out. ----
    {
        int c = tid, g = 0;
        #pragma unroll
        for (int k = 0; k < 3; ++k) {
            if (g < G) {
                int pi = lut[c];
                float em = emp_p[g][pi];
                float ne = emp_p[g][pi - GO_HP] + emp_p[g][pi + GO_HP]
                         + emp_p[g][pi - 1]     + emp_p[g][pi + 1];
                float nc = cur_p[g][pi - GO_HP] + cur_p[g][pi + GO_HP]
                         + cur_p[g][pi - 1]     + cur_p[g][pi + 1];
                float nw = weak_p[g][pi - GO_HP] + weak_p[g][pi + GO_HP]
                         + weak_p[g][pi - 1]     + weak_p[g][pi + 1];

                bool legal = (em > 0.5f) && (ne > 0.f || nw > 0.f);
                if (c == koc_s[g]) legal = false;

                size_t ob = (size_t)(gb + g) * (5 * NCELL);
                out[ob + c]             = cur_p[g][pi];
                out[ob + NCELL + c]     = opp_p[g][pi];
                out[ob + 2 * NCELL + c] = legal ? 1.f : 0.f;
                out[ob + 3 * NCELL + c] = nc * em;
                out[ob + 4 * NCELL + c] = (float)cp_s[g];
            }
            c += 256; if (c >= NCELL) { c -= NCELL; ++g; }
        }
    }
}

extern "C" void kernel_launch(void* const* d_in, const int* in_sizes, int n_in,
                              void* d_out, int out_size, void* d_ws, size_t ws_size,
                              hipStream_t stream) {
    const float* stones     = (const float*)d_in[0];
    const int*   cur_player = (const int*)d_in[1];
    const int*   ko         = (const int*)d_in[2];
    float*       out        = (float*)d_out;

    const int B = in_sizes[1];   // current_player has B elements
    go_features_kernel<<<B / G, 256, 0, stream>>>(stones, cur_player, ko, out);
}